// Round 12
// baseline (73.463 us; speedup 1.0000x reference)
//
#include <hip/hip_runtime.h>

// ParaModel_69664369541839: match = v1 @ v2^T [B,L1,L2]; masked row/col max;
// s = -max/100 masked; softmax; attention-pool p1,p2; cosine(p1,p2).
// B=128, L1=L2=256, D=768, fp32 in/out.
//
// R12 = R11 + RAW BARRIER (the actual T3/T4 fix). Root cause of six rounds of
// flat K1: __syncthreads() lowers to s_waitcnt vmcnt(0) lgkmcnt(0) + s_barrier,
// draining the just-issued next-tile loads EVERY iteration — full HBM latency
// exposed 12x regardless of staging scheme. Fix: lgkmcnt(0)-only drain + raw
// __builtin_amdgcn_s_barrier() (LDS writes visible; register-destined global
// loads stay in flight; DSWRITE's reg deps give the counted vmcnt(6)).
// Everything else identical to R11.

#define B_   128
#define L_   256
#define D_   768
#define NEGV (-10000.0f)

typedef _Float16 f16x8 __attribute__((ext_vector_type(8)));
typedef __fp16   h16x2 __attribute__((ext_vector_type(2)));
typedef float    f32x4 __attribute__((ext_vector_type(4)));

#define BTR  128          // rows per block (half of L1)
#define BKF  64           // fp32 k-elems per staged tile (2 MFMA K-steps)
#define NKT  (D_ / BKF)   // 12 (even)
#define LDH  72           // halves per LDS row (144B: conflict-light read pattern)

__device__ __forceinline__ unsigned fmap(float f) {
    unsigned u = __float_as_uint(f);
    return (u & 0x80000000u) ? ~u : (u | 0x80000000u);   // monotone float->uint
}
__device__ __forceinline__ float fdecode(unsigned u) {
    return __uint_as_float((u & 0x80000000u) ? (u ^ 0x80000000u) : ~u);
}
__device__ __forceinline__ float wred_max(float v) {
    #pragma unroll
    for (int o = 32; o; o >>= 1) v = fmaxf(v, __shfl_xor(v, o));
    return v;
}
__device__ __forceinline__ float wred_sum(float v) {
    #pragma unroll
    for (int o = 32; o; o >>= 1) v += __shfl_xor(v, o);
    return v;
}
__device__ __forceinline__ f16x8 cvt8(float4 a, float4 b) {
    union { h16x2 h2[4]; f16x8 h8; } u;
    u.h2[0] = __builtin_amdgcn_cvt_pkrtz(a.x, a.y);
    u.h2[1] = __builtin_amdgcn_cvt_pkrtz(a.z, a.w);
    u.h2[2] = __builtin_amdgcn_cvt_pkrtz(b.x, b.y);
    u.h2[3] = __builtin_amdgcn_cvt_pkrtz(b.z, b.w);
    return u.h8;
}

// Raw barrier: drain LDS (correctness) but NOT vmcnt (loads ride across).
#define BARRIER() do {                                        \
    __builtin_amdgcn_sched_barrier(0);                        \
    asm volatile("s_waitcnt lgkmcnt(0)" ::: "memory");        \
    __builtin_amdgcn_s_barrier();                             \
    __builtin_amdgcn_sched_barrier(0);                        \
} while (0)

// K1: per (b, rh): 128x256 match tile via fp16 MFMA.
// Row-max complete -> rmax[b][row]. Col-max partial -> cmax_p[b][rh][col].
__global__ __launch_bounds__(1024, 1)
void k_match(const float* __restrict__ v1, const float* __restrict__ m1,
             const float* __restrict__ v2, const float* __restrict__ m2,
             float* __restrict__ rmax, float* __restrict__ cmax_p)
{
    __shared__ __align__(16) _Float16 As[2][BTR * LDH];  // 2 x 18.4 KB
    __shared__ __align__(16) _Float16 Bs[2][L_ * LDH];   // 2 x 36.9 KB
    __shared__ unsigned rU[BTR], cU[L_];
    __shared__ float m1s[BTR], m2s[L_];

    // bijective XCD swizzle: 256 blocks, 32/XCD; a batch's 2 blocks adjacent
    const int bid = blockIdx.x;
    const int wg  = (bid & 7) * 32 + (bid >> 3);
    const int b = wg >> 1, rh = wg & 1;

    const int t = threadIdx.x;
    const int lane = t & 63, w = t >> 6;      // 16 waves
    const int wr = w >> 2, wc = w & 3;        // wave tile: 32 rows x 64 cols
    const int fr = lane & 15, fg = lane >> 4;

    if (t < BTR) { rU[t] = 0u; m1s[t] = m1[b * L_ + rh * BTR + t]; }
    if (t < L_)  { cU[t] = 0u; m2s[t] = m2[b * L_ + t]; }

    // staging: A tile 128x64 f32 -> thread owns row t>>3, cols (t&7)*8..+8
    //          B tile 256x64 f32 -> thread owns row t>>2, cols (t&3)*16..+16
    const int a_r = t >> 3, a_c = (t & 7) * 8;
    const int b_r = t >> 2, b_c = (t & 3) * 16;
    const float* ga = v1 + ((size_t)b * L_ + rh * BTR + a_r) * D_ + a_c;
    const float* gb = v2 + ((size_t)b * L_ + b_r) * D_ + b_c;

    // TWO named staging sets (2-deep pipeline, 12 float4 = 48 VGPR)
    float4 raA[2], rbA[4], raB[2], rbB[4];

    #define GLOADS(RA, RB, kt) do {                                           \
        const float* A_ = ga + (kt) * BKF;                                    \
        const float* C_ = gb + (kt) * BKF;                                    \
        RA[0] = *(const float4*)(A_);      RA[1] = *(const float4*)(A_ + 4);  \
        RB[0] = *(const float4*)(C_);      RB[1] = *(const float4*)(C_ + 4);  \
        RB[2] = *(const float4*)(C_ + 8);  RB[3] = *(const float4*)(C_ + 12); \
    } while (0)

    #define DSWRITES(RA, RB, buf) do {                                        \
        *(f16x8*)&As[buf][a_r * LDH + a_c] = cvt8(RA[0], RA[1]);              \
        _Float16* db = &Bs[buf][b_r * LDH + b_c];                             \
        *(f16x8*)db       = cvt8(RB[0], RB[1]);                               \
        *(f16x8*)(db + 8) = cvt8(RB[2], RB[3]);                               \
    } while (0)

    #define COMPUTE(buf) do {                                                 \
        _Pragma("unroll")                                                     \
        for (int ks = 0; ks < 2; ++ks) {                                      \
            f16x8 af[2], bf[4];                                               \
            _Pragma("unroll")                                                 \
            for (int i = 0; i < 2; ++i) {                                     \
                int r1 = wr * 32 + i * 16 + fr;                               \
                af[i] = *(const f16x8*)&As[buf][r1 * LDH + ks * 32 + fg * 8]; \
            }                                                                 \
            _Pragma("unroll")                                                 \
            for (int j = 0; j < 4; ++j) {                                     \
                int r2 = wc * 64 + j * 16 + fr;                               \
                bf[j] = *(const f16x8*)&Bs[buf][r2 * LDH + ks * 32 + fg * 8]; \
            }                                                                 \
            _Pragma("unroll")                                                 \
            for (int i = 0; i < 2; ++i)                                       \
                _Pragma("unroll")                                             \
                for (int j = 0; j < 4; ++j)                                   \
                    acc[i][j] = __builtin_amdgcn_mfma_f32_16x16x32_f16(af[i], bf[j], acc[i][j], 0, 0, 0); \
        }                                                                     \
    } while (0)

    f32x4 acc[2][4] = {};
    GLOADS(raA, rbA, 0);                      // tile 0 -> set A
    GLOADS(raB, rbB, 1);                      // tile 1 -> set B (stays in flight)
    DSWRITES(raA, rbA, 0);                    // tile 0 -> buf 0 (vmcnt(6) wait)
    BARRIER();
    int cur = 0;
    #pragma unroll
    for (int kp = 0; kp < NKT; kp += 2) {
        // ---- even iter: compute tile kp from buf cur ----
        if (kp + 2 < NKT) GLOADS(raA, rbA, kp + 2);   // set A free -> tile kp+2
        __builtin_amdgcn_sched_barrier(0);
        COMPUTE(cur);
        __builtin_amdgcn_sched_barrier(0);
        DSWRITES(raB, rbB, cur ^ 1);                  // tile kp+1; vmcnt(6) (A in flight)
        BARRIER();                                    // loads NOT drained
        cur ^= 1;
        // ---- odd iter: compute tile kp+1 ----
        if (kp + 3 < NKT) GLOADS(raB, rbB, kp + 3);   // set B free -> tile kp+3
        __builtin_amdgcn_sched_barrier(0);
        COMPUTE(cur);
        __builtin_amdgcn_sched_barrier(0);
        if (kp + 2 < NKT) DSWRITES(raA, rbA, cur ^ 1);// tile kp+2; vmcnt(6)
        BARRIER();
        cur ^= 1;
    }
    #undef GLOADS
    #undef DSWRITES
    #undef COMPUTE

    // masked row/col max (C/D: row = wr*32 + i*16 + fg*4 + r, col = wc*64 + j*16 + fr)
    #pragma unroll
    for (int i = 0; i < 2; ++i)
        #pragma unroll
        for (int r = 0; r < 4; ++r) {
            int row = wr * 32 + i * 16 + fg * 4 + r;
            bool rv = m1s[row] > 0.f;
            float mx = NEGV;
            #pragma unroll
            for (int j = 0; j < 4; ++j) {
                int col = wc * 64 + j * 16 + fr;
                float vv = (rv && m2s[col] > 0.f) ? acc[i][j][r] : NEGV;
                mx = fmaxf(mx, vv);
            }
            atomicMax(&rU[row], fmap(mx));    // LDS-local only
        }
    #pragma unroll
    for (int j = 0; j < 4; ++j) {
        int col = wc * 64 + j * 16 + fr;
        bool cv = m2s[col] > 0.f;
        float mx = NEGV;
        #pragma unroll
        for (int i = 0; i < 2; ++i)
            #pragma unroll
            for (int r = 0; r < 4; ++r) {
                int row = wr * 32 + i * 16 + fg * 4 + r;
                float vv = (cv && m1s[row] > 0.f) ? acc[i][j][r] : NEGV;
                mx = fmaxf(mx, vv);
            }
        atomicMax(&cU[col], fmap(mx));        // LDS-local only
    }
    __syncthreads();

    // complete row-max for this half (plain store); partial col-max per rh
    if (t < BTR)                rmax[b * L_ + rh * BTR + t] = fdecode(rU[t]);
    else if (t < BTR + L_)      cmax_p[((size_t)b * 2 + rh) * L_ + (t - BTR)] = fdecode(cU[t - BTR]);
}

// K2: per (b, side, chunk): softmax over 256 logits (redundant per chunk, cheap)
// + pool of 256 dims. 768 blocks.
__global__ __launch_bounds__(256)
void k_attn_pool(const float* __restrict__ v1, const float* __restrict__ m1,
                 const float* __restrict__ v2, const float* __restrict__ m2,
                 const float* __restrict__ rmax, const float* __restrict__ cmax_p,
                 float* __restrict__ pout)
{
    // XCD swizzle: 768 blocks -> 96/XCD -> consecutive batches per XCD
    const int lin = (int)blockIdx.x;
    const int swz = (lin & 7) * 96 + (lin >> 3);
    const int b = swz / 6, rem = swz % 6, side = rem / 3, chunk = rem % 3;

    const float* v  = side ? v2 : v1;
    const float* mk = side ? m2 : m1;
    const int t = threadIdx.x, lane = t & 63, w = t >> 6;

    __shared__ float attn[L_];
    __shared__ float sred[4];

    float mkv = mk[b * L_ + t];
    float mxv = side ? fmaxf(cmax_p[((size_t)b * 2) * L_ + t],
                             cmax_p[((size_t)b * 2 + 1) * L_ + t])
                     : rmax[b * L_ + t];
    float s = (mkv > 0.f) ? (-mxv * 0.01f) : NEGV;

    float wm = wred_max(s);
    if (lane == 0) sred[w] = wm;
    __syncthreads();
    float mx = fmaxf(fmaxf(sred[0], sred[1]), fmaxf(sred[2], sred[3]));
    float e = expf(s - mx);
    __syncthreads();
    float ws = wred_sum(e);
    if (lane == 0) sred[w] = ws;
    __syncthreads();
    float sum = sred[0] + sred[1] + sred[2] + sred[3];
    attn[t] = e / sum;
    __syncthreads();

    const int d = chunk * 256 + t;
    const float* vb = v + (size_t)b * L_ * D_ + d;
    float p = 0.f;
    #pragma unroll 8
    for (int l = 0; l < L_; ++l) p += attn[l] * vb[(size_t)l * D_];
    pout[((size_t)b * 2 + side) * D_ + d] = p;
}

// K3: per batch: cosine similarity of p1, p2.
__global__ __launch_bounds__(256)
void k_cos(const float* __restrict__ pout, float* __restrict__ out)
{
    const int b = blockIdx.x, t = threadIdx.x, lane = t & 63, w = t >> 6;
    const float* p1 = pout + (size_t)b * 2 * D_;
    const float* p2 = p1 + D_;
    float dot = 0.f, n1 = 0.f, n2 = 0.f;
    for (int d = t; d < D_; d += 256) {
        float a = p1[d], c = p2[d];
        dot += a * c; n1 += a * a; n2 += c * c;
    }
    dot = wred_sum(dot); n1 = wred_sum(n1); n2 = wred_sum(n2);
    __shared__ float sd[4], sa[4], sc[4];
    if (lane == 0) { sd[w] = dot; sa[w] = n1; sc[w] = n2; }
    __syncthreads();
    if (t == 0) {
        float dd = sd[0] + sd[1] + sd[2] + sd[3];
        float aa = sa[0] + sa[1] + sa[2] + sa[3];
        float cc = sc[0] + sc[1] + sc[2] + sc[3];
        out[b] = dd / (fmaxf(sqrtf(aa), 1e-8f) * fmaxf(sqrtf(cc), 1e-8f));
    }
}

extern "C" void kernel_launch(void* const* d_in, const int* in_sizes, int n_in,
                              void* d_out, int out_size, void* d_ws, size_t ws_size,
                              hipStream_t stream)
{
    const float* v1 = (const float*)d_in[0];
    const float* m1 = (const float*)d_in[1];
    const float* v2 = (const float*)d_in[2];
    const float* m2 = (const float*)d_in[3];
    float* out = (float*)d_out;

    float* rmax   = (float*)d_ws;                       // [B][256] complete row-max
    float* cmax_p = rmax + (size_t)B_ * L_;             // [B][2][256] col-max partials
    float* pout   = cmax_p + (size_t)B_ * 2 * L_;       // [B][2][768] pooled vectors

    k_match<<<dim3(2 * B_), 1024, 0, stream>>>(v1, m1, v2, m2, rmax, cmax_p);

    k_attn_pool<<<dim3(B_ * 2 * 3), 256, 0, stream>>>(v1, m1, v2, m2, rmax, cmax_p, pout);

    k_cos<<<B_, 256, 0, stream>>>(pout, out);
}